// Round 13
// baseline (724.641 us; speedup 1.0000x reference)
//
#include <hip/hip_runtime.h>

typedef _Float16 h4 __attribute__((ext_vector_type(4)));
typedef _Float16 h8 __attribute__((ext_vector_type(8)));
typedef __fp16 g2 __attribute__((ext_vector_type(2)));
typedef float f4 __attribute__((ext_vector_type(4)));

#define MFMA16(a, b, c) __builtin_amdgcn_mfma_f32_16x16x32_f16((a), (b), (c), 0, 0, 0)

static constexpr int TT  = 1024;
static constexpr int BS  = 1024;
static constexpr int LCH = 16;   // chunk length
static constexpr int NCH = 64;   // chunks
static constexpr size_t XTOT = (size_t)TT * BS * 128;

// workspace byte offsets
static constexpr size_t WS_WT16 = 0;       // 128x128 f16 : W_eff^T (S row-major)
static constexpr size_t WS_HF1  = 32768;
static constexpr size_t WS_HF2  = 49152;
static constexpr size_t WS_BW   = 65536;
static constexpr size_t WS_EW   = 81920;
static constexpr size_t WS_FACT = 90112;   // 8 x 16384 f16: T1,U1,T2,U2,T4,U4,T8,U8
static constexpr size_t WS_POW  = 352256;  // 16 x 16384 f16: (W^p)^T, p=1..16
static constexpr size_t WS_F    = 876544;                               // NCH f32 slots
static constexpr size_t WS_INIT = WS_F + (size_t)NCH * BS * 128 * 4;    // NCH f32 slots
static constexpr size_t WS_XL   = WS_INIT + (size_t)NCH * BS * 128 * 4; // T*B*128 f16

template <typename T>
__device__ inline T ntload(const T* p) { return __builtin_nontemporal_load(p); }

__device__ inline h4 pk4(f4 a) {  // RTZ packed (MLP path only)
    g2 p0 = __builtin_amdgcn_cvt_pkrtz(a[0], a[1]);
    g2 p1 = __builtin_amdgcn_cvt_pkrtz(a[2], a[3]);
    h4 r;
    r[0] = (_Float16)p0[0]; r[1] = (_Float16)p0[1];
    r[2] = (_Float16)p1[0]; r[3] = (_Float16)p1[1];
    return r;
}
__device__ inline f4 relu4(f4 a) {
    f4 r;
#pragma unroll
    for (int j = 0; j < 4; ++j) r[j] = fmaxf(a[j], 0.f);
    return r;
}

// ---------------------------------------------------------------------------
// prep: W_eff (softmax+scale, stored transposed = S row-major) + f16 weights
// ---------------------------------------------------------------------------
__global__ void prep_kernel(const float* __restrict__ Aw, const float* __restrict__ As,
                            const float* __restrict__ hf1, const float* __restrict__ hf2,
                            const float* __restrict__ Bw, const float* __restrict__ Ew,
                            char* __restrict__ ws)
{
    const int tid = threadIdx.x;  // 128
    const int bid = blockIdx.x;   // 160
    if (bid < 128) {
        __shared__ float red[128];
        const int n = bid;
        const float a = Aw[n * 128 + tid];
        red[tid] = a;
        __syncthreads();
        for (int s = 64; s > 0; s >>= 1) {
            if (tid < s) red[tid] = fmaxf(red[tid], red[tid + s]);
            __syncthreads();
        }
        const float mx = red[0];
        __syncthreads();
        const float e = expf(a - mx);
        red[tid] = e;
        __syncthreads();
        for (int s = 64; s > 0; s >>= 1) {
            if (tid < s) red[tid] += red[tid + s];
            __syncthreads();
        }
        const float sm  = e / red[0];
        const float asv = As[n * 128 + tid];
        const float sc  = 1.0f - 0.1f * (1.0f / (1.0f + expf(-asv)));
        ((_Float16*)(ws + WS_WT16))[n * 128 + tid] = (_Float16)(sc * sm);
    } else {
        const int b2 = bid - 128;  // 32 blocks
        for (int i = b2 * 128 + tid; i < 8192; i += 32 * 128) {
            ((_Float16*)(ws + WS_HF1))[i] = (_Float16)hf1[i];
            ((_Float16*)(ws + WS_HF2))[i] = (_Float16)hf2[i];
            ((_Float16*)(ws + WS_BW))[i]  = (_Float16)Bw[i];
            if (i < 4096) ((_Float16*)(ws + WS_EW))[i] = (_Float16)Ew[i];
        }
    }
}

// ---------------------------------------------------------------------------
// sq_kernel: dual-chain squarings -> FACT pairs (T,U) for W^{1,2,4,8}.
// T_f=(W^f)^T, U_f=W^f. (Verified R7/R8 pattern.)
// ---------------------------------------------------------------------------
__global__ void sq_kernel(char* __restrict__ ws)
{
    const int tid  = threadIdx.x;
    const int lane = tid & 63;
    const int w    = tid >> 6;
    const int cl   = lane & 15;
    const int gq   = lane >> 4;
    constexpr int LDP = 136;

    __shared__ __align__(16) _Float16 G[2][128 * LDP];
    __shared__ __align__(16) _Float16 H[2][128 * LDP];

    const _Float16* Wt16 = (const _Float16*)(ws + WS_WT16);
    _Float16* FACT       = (_Float16*)(ws + WS_FACT);

    for (int i = tid; i < 2048; i += 256) {
        h8 v = *(const h8*)&Wt16[i * 8];
        *(h8*)&G[0][(i >> 4) * LDP + (i & 15) * 8] = v;
        *(h8*)&FACT[i * 8] = v;  // T1
    }
    __syncthreads();
    for (int i = tid; i < 16384; i += 256) {
        const int r = i >> 7, cc = i & 127;
        H[0][cc * LDP + r] = G[0][r * LDP + cc];
    }
    __syncthreads();
    for (int i = tid; i < 2048; i += 256)  // U1
        *(h8*)&FACT[16384 + i * 8] = *(const h8*)&H[0][(i >> 4) * LDP + (i & 15) * 8];

    int cur = 0;
    for (int s = 0; s < 3; ++s) {  // W^2, W^4, W^8
        const _Float16* Gs = G[cur];
        const _Float16* Hs = H[cur];
        _Float16* Gd = G[cur ^ 1];
        _Float16* Hd = H[cur ^ 1];
        f4 aG[8][2], aH[8][2];
#pragma unroll
        for (int mt = 0; mt < 8; ++mt)
#pragma unroll
            for (int nt = 0; nt < 2; ++nt) { aG[mt][nt] = f4{}; aH[mt][nt] = f4{}; }
#pragma unroll
        for (int kk = 0; kk < 4; ++kk) {
            h8 bG0 = *(const h8*)&Hs[((w * 2 + 0) * 16 + cl) * LDP + kk * 32 + gq * 8];
            h8 bG1 = *(const h8*)&Hs[((w * 2 + 1) * 16 + cl) * LDP + kk * 32 + gq * 8];
            h8 bH0 = *(const h8*)&Gs[((w * 2 + 0) * 16 + cl) * LDP + kk * 32 + gq * 8];
            h8 bH1 = *(const h8*)&Gs[((w * 2 + 1) * 16 + cl) * LDP + kk * 32 + gq * 8];
#pragma unroll
            for (int mt = 0; mt < 8; ++mt) {
                h8 ag = *(const h8*)&Gs[(mt * 16 + cl) * LDP + kk * 32 + gq * 8];
                h8 ah = *(const h8*)&Hs[(mt * 16 + cl) * LDP + kk * 32 + gq * 8];
                aG[mt][0] = MFMA16(ag, bG0, aG[mt][0]);
                aG[mt][1] = MFMA16(ag, bG1, aG[mt][1]);
                aH[mt][0] = MFMA16(ah, bH0, aH[mt][0]);
                aH[mt][1] = MFMA16(ah, bH1, aH[mt][1]);
            }
        }
        __syncthreads();
#pragma unroll
        for (int mt = 0; mt < 8; ++mt)
#pragma unroll
            for (int nt = 0; nt < 2; ++nt) {
                h4 hg, hh;
#pragma unroll
                for (int r = 0; r < 4; ++r) {
                    hg[r] = (_Float16)aG[mt][nt][r];
                    hh[r] = (_Float16)aH[mt][nt][r];
                }
                const int col  = (w * 2 + nt) * 16 + cl;
                const int rowb = mt * 16 + gq * 4;
                *(h4*)&Hd[col * LDP + rowb] = hg;   // U_{2f}
                *(h4*)&Gd[col * LDP + rowb] = hh;   // T_{2f}
            }
        __syncthreads();
        cur ^= 1;
        const size_t toff = (size_t)(2 * (s + 1)) * 16384;       // T_{2^{s+1}}
        for (int i = tid; i < 2048; i += 256) {
            *(h8*)&FACT[toff + i * 8] =
                *(const h8*)&G[cur][(i >> 4) * LDP + (i & 15) * 8];
            *(h8*)&FACT[toff + 16384 + i * 8] =
                *(const h8*)&H[cur][(i >> 4) * LDP + (i & 15) * 8];
        }
        __syncthreads();
    }
}

// ---------------------------------------------------------------------------
// prod_kernel: block p-1 computes POW[p-1] = T_p = (W^p)^T from binary
// factors (<=3 chained dual products; powers of W commute).
// ---------------------------------------------------------------------------
__global__ void prod_kernel(char* __restrict__ ws)
{
    const int tid  = threadIdx.x;
    const int lane = tid & 63;
    const int w    = tid >> 6;
    const int cl   = lane & 15;
    const int gq   = lane >> 4;
    const int p    = blockIdx.x + 1;  // 1..16
    constexpr int LDP = 136;

    const _Float16* FACT = (const _Float16*)(ws + WS_FACT);
    _Float16* POW        = (_Float16*)(ws + WS_POW);

    int fl[4], nf = 0;
    if (p == 16) { fl[0] = 8; fl[1] = 8; nf = 2; }
    else { for (int b = 8; b >= 1; b >>= 1) if (p & b) fl[nf++] = b; }

    if (nf == 1) {  // p in {1,2,4,8}: copy T_p directly
        const int fi = (p == 1) ? 0 : (p == 2) ? 1 : (p == 4) ? 2 : 3;
        for (int i = tid; i < 2048; i += 256)
            *(h8*)&POW[(size_t)(p - 1) * 16384 + i * 8] =
                *(const h8*)&FACT[(size_t)(2 * fi) * 16384 + i * 8];
        return;
    }

    __shared__ __align__(16) _Float16 TA[128 * LDP], UA[128 * LDP];
    __shared__ __align__(16) _Float16 TB[128 * LDP], UB[128 * LDP];

    auto fidx = [](int f) { return (f == 1) ? 0 : (f == 2) ? 1 : (f == 4) ? 2 : 3; };
    auto loadpair = [&](int f, _Float16* T, _Float16* U) {
        const size_t toff = (size_t)(2 * fidx(f)) * 16384;
        for (int i = tid; i < 2048; i += 256) {
            *(h8*)&T[(i >> 4) * LDP + (i & 15) * 8] = *(const h8*)&FACT[toff + i * 8];
            *(h8*)&U[(i >> 4) * LDP + (i & 15) * 8] =
                *(const h8*)&FACT[toff + 16384 + i * 8];
        }
    };

    loadpair(fl[0], TA, UA);   // R = W^{fl[0]}
    _Float16 *Tc = TA, *Uc = UA, *To = TB, *Uo = UB;

    for (int j = 1; j < nf; ++j) {
        loadpair(fl[j], To, Uo);  // factor F
        __syncthreads();
        // aA = T_F · T_R  (= T_{R·F});  aB = U_R · U_F  (= U_{R·F})
        f4 aA[8][2], aB[8][2];
#pragma unroll
        for (int mt = 0; mt < 8; ++mt)
#pragma unroll
            for (int nt = 0; nt < 2; ++nt) { aA[mt][nt] = f4{}; aB[mt][nt] = f4{}; }
#pragma unroll
        for (int kk = 0; kk < 4; ++kk) {
            h8 bA0 = *(const h8*)&Uc[((w * 2 + 0) * 16 + cl) * LDP + kk * 32 + gq * 8];
            h8 bA1 = *(const h8*)&Uc[((w * 2 + 1) * 16 + cl) * LDP + kk * 32 + gq * 8];
            h8 bB0 = *(const h8*)&To[((w * 2 + 0) * 16 + cl) * LDP + kk * 32 + gq * 8];
            h8 bB1 = *(const h8*)&To[((w * 2 + 1) * 16 + cl) * LDP + kk * 32 + gq * 8];
#pragma unroll
            for (int mt = 0; mt < 8; ++mt) {
                h8 aT = *(const h8*)&To[(mt * 16 + cl) * LDP + kk * 32 + gq * 8];
                h8 aU = *(const h8*)&Uc[(mt * 16 + cl) * LDP + kk * 32 + gq * 8];
                aA[mt][0] = MFMA16(aT, bA0, aA[mt][0]);
                aA[mt][1] = MFMA16(aT, bA1, aA[mt][1]);
                aB[mt][0] = MFMA16(aU, bB0, aB[mt][0]);
                aB[mt][1] = MFMA16(aU, bB1, aB[mt][1]);
            }
        }
        __syncthreads();
#pragma unroll
        for (int mt = 0; mt < 8; ++mt)
#pragma unroll
            for (int nt = 0; nt < 2; ++nt) {
                h4 hA, hB;
#pragma unroll
                for (int r = 0; r < 4; ++r) {
                    hA[r] = (_Float16)aA[mt][nt][r];
                    hB[r] = (_Float16)aB[mt][nt][r];
                }
                const int col  = (w * 2 + nt) * 16 + cl;
                const int rowb = mt * 16 + gq * 4;
                *(h4*)&Uo[col * LDP + rowb] = hA;   // U_{R·F} = (T_{R·F})^T-write
                *(h4*)&To[col * LDP + rowb] = hB;   // T_{R·F}
            }
        __syncthreads();
        _Float16* t;
        t = Tc; Tc = To; To = t;
        t = Uc; Uc = Uo; Uo = t;
    }
    for (int i = tid; i < 2048; i += 256)
        *(h8*)&POW[(size_t)(p - 1) * 16384 + i * 8] =
            *(const h8*)&Tc[(i >> 4) * LDP + (i & 15) * 8];
}

// ---------------------------------------------------------------------------
// K1: fused MLP + LOCAL scan (zero init), chunk=16 t x 16 b, 4 waves n-split.
// Streams Xl (f16 RNE, fragment order); F[c] (f32) at k=15.
// ---------------------------------------------------------------------------
__global__ __launch_bounds__(256, 1)
void fused_local(const float* __restrict__ Mfl, const float* __restrict__ DTi,
                 const float* __restrict__ Din, char* __restrict__ ws)
{
    const int tid  = threadIdx.x;
    const int lane = tid & 63;
    const int w    = tid >> 6;
    const int cl   = lane & 15;
    const int gq   = lane >> 4;
    const int bt   = blockIdx.x & 63;
    const int c    = blockIdx.x >> 6;   // 0..63
    const int b0   = bt * 16;

    const _Float16* Hf1  = (const _Float16*)(ws + WS_HF1);
    const _Float16* Hf2  = (const _Float16*)(ws + WS_HF2);
    const _Float16* Bw16 = (const _Float16*)(ws + WS_BW);
    const _Float16* Ew16 = (const _Float16*)(ws + WS_EW);
    const _Float16* Wt16 = (const _Float16*)(ws + WS_WT16);
    float* Fbuf          = (float*)(ws + WS_F);
    _Float16* XL         = (_Float16*)(ws + WS_XL);

    __shared__ __align__(16) _Float16 mds[4][16 * 64];
    __shared__ __align__(16) _Float16 dts[4][16 * 32];
    __shared__ __align__(16) _Float16 hs[4][16 * 128];
    __shared__ __align__(16) _Float16 us[4][16 * 64];
    __shared__ __align__(16) _Float16 xsh[2][16 * 128];

    h8 hf1f[2][2], bwf[2][2], ewf[2], hf2f[4];
#pragma unroll
    for (int nt = 0; nt < 2; ++nt) {
        const int ng = w * 32 + nt * 16 + cl;
#pragma unroll
        for (int kk = 0; kk < 2; ++kk) {
            hf1f[nt][kk] = *(const h8*)&Hf1[ng * 64 + kk * 32 + gq * 8];
            bwf[nt][kk]  = *(const h8*)&Bw16[ng * 64 + kk * 32 + gq * 8];
        }
        ewf[nt] = *(const h8*)&Ew16[ng * 32 + gq * 8];
    }
    {
        const int ng = w * 16 + cl;
#pragma unroll
        for (int kk = 0; kk < 4; ++kk)
            hf2f[kk] = *(const h8*)&Hf2[ng * 128 + kk * 32 + gq * 8];
    }
    h8 wfp[2][4];
#pragma unroll
    for (int nt = 0; nt < 2; ++nt)
#pragma unroll
        for (int kt = 0; kt < 4; ++kt)
            wfp[nt][kt] =
                *(const h8*)&Wt16[(w * 32 + nt * 16 + cl) * 128 + kt * 32 + gq * 8];

    {
        h8 z = {};
        *(h8*)&xsh[0][tid * 8] = z;
    }

    const int qrow = (tid & 127) >> 3;
    const int qc4  = (tid & 7) * 4;
    f4 pm[4], pd[4];
    auto GLOAD = [&](int g) {
#pragma unroll
        for (int s = 0; s < 4; ++s) {
            const size_t t  = (size_t)c * LCH + g * 4 + s;
            const size_t rb = (t * BS + b0 + qrow) * 32 + qc4;
            pm[s] = (tid < 128) ? ntload((const f4*)&Mfl[rb]) : ntload((const f4*)&DTi[rb]);
            if (tid < 128) pd[s] = ntload((const f4*)&Din[rb]);
        }
    };
    GLOAD(0);

    _Float16* xcur = xsh[0];
    _Float16* xnxt = xsh[1];

    for (int g = 0; g < 4; ++g) {
#pragma unroll
        for (int s = 0; s < 4; ++s) {
            const int col = (tid < 128) ? qc4 : (32 + qc4);
            h4 hv = pk4(pm[s]);
            *(h4*)&mds[s][qrow * 64 + (((col >> 3) ^ (qrow & 7)) * 8) + (col & 7)] = hv;
            if (tid < 128) {
                h4 h2v = pk4(pd[s]);
                *(h4*)&dts[s][qrow * 32 + (((qc4 >> 3) ^ (qrow & 3)) * 8) + (qc4 & 7)] = h2v;
            }
        }
        if (g < 3) GLOAD(g + 1);
        __syncthreads();

        // G1
#pragma unroll
        for (int s = 0; s < 4; ++s) {
            f4 ha0 = {}, ha1 = {};
#pragma unroll
            for (int kk = 0; kk < 2; ++kk) {
                h8 a = *(const h8*)&mds[s][cl * 64 + (((kk * 4 + gq) ^ (cl & 7)) * 8)];
                ha0 = MFMA16(hf1f[0][kk], a, ha0);
                ha1 = MFMA16(hf1f[1][kk], a, ha1);
            }
#pragma unroll
            for (int nt = 0; nt < 2; ++nt) {
                const int nb8 = w * 4 + nt * 2 + (gq >> 1);
                h4 hv = pk4(relu4(nt ? ha1 : ha0));
                *(h4*)&hs[s][cl * 128 + ((nb8 ^ cl) & 15) * 8 + (gq & 1) * 4] = hv;
            }
        }
        __syncthreads();

        // G2
#pragma unroll
        for (int s = 0; s < 4; ++s) {
            f4 ua = {};
#pragma unroll
            for (int kt = 0; kt < 4; ++kt) {
                h8 a = *(const h8*)&hs[s][cl * 128 + (((kt * 4 + gq) ^ cl) & 15) * 8];
                ua = MFMA16(hf2f[kt], a, ua);
            }
            const int ub8 = w * 2 + (gq >> 1);
            h4 uv = pk4(relu4(ua));
            *(h4*)&us[s][cl * 64 + ((ub8 ^ (cl & 7)) & 7) * 8 + (gq & 1) * 4] = uv;
        }
        __syncthreads();

        // G3 -> dv (h4 regs)
        h4 dv0[4], dv1[4];
#pragma unroll
        for (int s = 0; s < 4; ++s) {
            f4 a20 = {}, a21 = {};
#pragma unroll
            for (int kk = 0; kk < 2; ++kk) {
                h8 a = *(const h8*)&us[s][cl * 64 + (((kk * 4 + gq) ^ (cl & 7)) & 7) * 8];
                a20 = MFMA16(bwf[0][kk], a, a20);
                a21 = MFMA16(bwf[1][kk], a, a21);
            }
            {
                h8 ad = *(const h8*)&dts[s][cl * 32 + ((gq ^ (cl & 3)) * 8)];
                a20 = MFMA16(ewf[0], ad, a20);
                a21 = MFMA16(ewf[1], ad, a21);
            }
            dv0[s] = pk4(a20);
            dv1[s] = pk4(a21);
        }

        // 4 local-scan steps
#pragma unroll
        for (int s = 0; s < 4; ++s) {
            h8 xf[4];
#pragma unroll
            for (int kt = 0; kt < 4; ++kt)
                xf[kt] = *(const h8*)&xcur[cl * 128 + (((kt * 4 + gq) ^ cl) & 15) * 8];
            f4 acc0, acc1;
#pragma unroll
            for (int r = 0; r < 4; ++r) {
                acc0[r] = (float)dv0[s][r];
                acc1[r] = (float)dv1[s][r];
            }
#pragma unroll
            for (int kt = 0; kt < 4; ++kt) {
                acc0 = MFMA16(wfp[0][kt], xf[kt], acc0);
                acc1 = MFMA16(wfp[1][kt], xf[kt], acc1);
            }

            // stream Xl (f16 RNE, fragment order)
            {
                const size_t t = (size_t)c * LCH + g * 4 + s;
                h8 o;
#pragma unroll
                for (int r = 0; r < 4; ++r) {
                    o[r]     = (_Float16)acc0[r];
                    o[4 + r] = (_Float16)acc1[r];
                }
                *(h8*)&XL[((t * 64 + bt) * 256 + tid) * 8] = o;
            }

            const bool last = (g == 3) && (s == 3);
            if (last) {
                float* fp = &Fbuf[((size_t)c * BS + b0 + cl) * 128 + w * 32 + gq * 4];
                *(f4*)fp = acc0;
                *(f4*)(fp + 16) = acc1;
            } else {
#pragma unroll
                for (int nt = 0; nt < 2; ++nt) {
                    h4 hv;
#pragma unroll
                    for (int r = 0; r < 4; ++r) hv[r] = (_Float16)(nt ? acc1[r] : acc0[r]);
                    const int nb8 = w * 4 + nt * 2 + (gq >> 1);
                    *(h4*)&xnxt[cl * 128 + ((nb8 ^ cl) & 15) * 8 + (gq & 1) * 4] = hv;
                }
                __syncthreads();
                _Float16* tmp = xcur; xcur = xnxt; xnxt = tmp;
            }
        }
    }
}

// ---------------------------------------------------------------------------
// K2: carry Init[cc] = Init[cc-1] @ W^16 + F[cc-1]; Init kept f32 (R11 code).
// ---------------------------------------------------------------------------
__global__ __launch_bounds__(64, 1)
void carry_kernel(const float* __restrict__ x0, char* __restrict__ ws)
{
    const int lane = threadIdx.x;
    const int cl = lane & 15, gq = lane >> 4;
    const int b0 = blockIdx.x * 16;

    const _Float16* W16 = (const _Float16*)(ws + WS_POW) + (size_t)15 * 16384;
    const float* Fbuf   = (const float*)(ws + WS_F);
    float* Init         = (float*)(ws + WS_INIT);

    __shared__ __align__(16) _Float16 tbuf[16 * 128];

    h8 wf[8][4];
#pragma unroll
    for (int nt = 0; nt < 8; ++nt)
#pragma unroll
        for (int kt = 0; kt < 4; ++kt)
            wf[nt][kt] = *(const h8*)&W16[(nt * 16 + cl) * 128 + kt * 32 + gq * 8];

    h8 xf[4];
    {
        f4 iv[8];
#pragma unroll
        for (int nt = 0; nt < 8; ++nt)
            iv[nt] = *(const f4*)&x0[(size_t)(b0 + cl) * 128 + nt * 16 + gq * 4];
#pragma unroll
        for (int nt = 0; nt < 8; ++nt)
            *(f4*)&Init[(size_t)(b0 + cl) * 128 + nt * 16 + gq * 4] = iv[nt];
#pragma unroll
        for (int nt = 0; nt < 8; ++nt) {
            h4 hv;
#pragma unroll
            for (int r = 0; r < 4; ++r) hv[r] = (_Float16)iv[nt][r];
            *(h4*)&tbuf[cl * 128 + (((nt * 2 + (gq >> 1)) ^ cl) & 15) * 8 + (gq & 1) * 4] = hv;
        }
#pragma unroll
        for (int kt = 0; kt < 4; ++kt)
            xf[kt] = *(const h8*)&tbuf[cl * 128 + (((kt * 4 + gq) ^ cl) & 15) * 8];
    }

    for (int cc = 1; cc < NCH; ++cc) {
        f4 acc[8];
#pragma unroll
        for (int nt = 0; nt < 8; ++nt)
            acc[nt] = *(const f4*)&Fbuf[((size_t)(cc - 1) * BS + b0 + cl) * 128 + nt * 16 + gq * 4];
#pragma unroll
        for (int kt = 0; kt < 4; ++kt)
#pragma unroll
            for (int nt = 0; nt < 8; ++nt)
                acc[nt] = MFMA16(wf[nt][kt], xf[kt], acc[nt]);
#pragma unroll
        for (int nt = 0; nt < 8; ++nt)
            *(f4*)&Init[((size_t)cc * BS + b0 + cl) * 128 + nt * 16 + gq * 4] = acc[nt];
        if (cc < NCH - 1) {
#pragma unroll
            for (int nt = 0; nt < 8; ++nt) {
                h4 hv;
#pragma unroll
                for (int r = 0; r < 4; ++r) hv[r] = (_Float16)acc[nt][r];
                *(h4*)&tbuf[cl * 128 + (((nt * 2 + (gq >> 1)) ^ cl) & 15) * 8 + (gq & 1) * 4] = hv;
            }
#pragma unroll
            for (int kt = 0; kt < 4; ++kt)
                xf[kt] = *(const h8*)&tbuf[cl * 128 + (((kt * 4 + gq) ^ cl) & 15) * 8];
        }
    }
}

// ---------------------------------------------------------------------------
// K3': correction. Block (k, bt): X[c*16+k] = Xl + Init_c @ W^{k+1}.
// Init read f32 (RNE convert in-register). No barriers/LDS; NT stores.
// ---------------------------------------------------------------------------
__global__ __launch_bounds__(256, 1)
void correct_kernel(char* __restrict__ ws, float* __restrict__ Xout,
                    float* __restrict__ Yout)
{
    const int tid  = threadIdx.x;
    const int lane = tid & 63;
    const int w    = tid >> 6;
    const int cl   = lane & 15;
    const int gq   = lane >> 4;
    const int k    = blockIdx.x >> 6;   // 0..15
    const int bt   = blockIdx.x & 63;
    const int b0   = bt * 16;

    const _Float16* Tk  = (const _Float16*)(ws + WS_POW) + (size_t)k * 16384;
    const float* Init   = (const float*)(ws + WS_INIT);
    const _Float16* XL  = (const _Float16*)(ws + WS_XL);

    h8 wfp[2][4];
#pragma unroll
    for (int nt = 0; nt < 2; ++nt)
#pragma unroll
        for (int kt = 0; kt < 4; ++kt)
            wfp[nt][kt] =
                *(const h8*)&Tk[(w * 32 + nt * 16 + cl) * 128 + kt * 32 + gq * 8];

    auto LOADC = [&](int c, h8* xf, h8& xl) {
        const float* ib = &Init[((size_t)c * BS + b0 + cl) * 128 + gq * 8];
#pragma unroll
        for (int kt = 0; kt < 4; ++kt) {
            f4 v0 = *(const f4*)&ib[kt * 32];
            f4 v1 = *(const f4*)&ib[kt * 32 + 4];
            h8 x;
#pragma unroll
            for (int r = 0; r < 4; ++r) {
                x[r]     = (_Float16)v0[r];
                x[4 + r] = (_Float16)v1[r];
            }
            xf[kt] = x;
        }
        const size_t t = (size_t)c * LCH + k;
        xl = *(const h8*)&XL[((t * 64 + bt) * 256 + tid) * 8];
    };

#define CSTEP(C, XF, XLR)                                                            \
    {                                                                                \
        f4 acc0, acc1;                                                               \
        _Pragma("unroll") for (int r = 0; r < 4; ++r) {                              \
            acc0[r] = (float)XLR[r];                                                 \
            acc1[r] = (float)XLR[4 + r];                                             \
        }                                                                            \
        _Pragma("unroll") for (int kt = 0; kt < 4; ++kt) {                           \
            acc0 = MFMA16(wfp[0][kt], XF[kt], acc0);                                 \
            acc1 = MFMA16(wfp[1][kt], XF[kt], acc1);                                 \
        }                                                                            \
        if ((C) + 2 < NCH) LOADC((C) + 2, XF, XLR);                                  \
        const size_t t = (size_t)(C) * LCH + k;                                      \
        float* xp = &Xout[(t * BS + b0 + cl) * 128 + w * 32 + gq * 4];               \
        __builtin_nontemporal_store(acc0, (f4*)xp);                                  \
        __builtin_nontemporal_store(acc1, (f4*)(xp + 16));                           \
        if (w == 3 && gq == 3)                                                       \
            __builtin_nontemporal_store(acc1[3], &Yout[t * BS + b0 + cl]);           \
    }

    h8 xfA[4], xfB[4], xlA, xlB;
    LOADC(0, xfA, xlA);
    LOADC(1, xfB, xlB);
    for (int c = 0; c < NCH; c += 2) {
        CSTEP(c, xfA, xlA);
        CSTEP(c + 1, xfB, xlB);
    }
#undef CSTEP
}

// ---------------------------------------------------------------------------
extern "C" void kernel_launch(void* const* d_in, const int* in_sizes, int n_in,
                              void* d_out, int out_size, void* d_ws, size_t ws_size,
                              hipStream_t stream)
{
    const float* x_in = (const float*)d_in[0];
    const float* Mfl  = (const float*)d_in[1];
    const float* DTi  = (const float*)d_in[2];
    const float* Din  = (const float*)d_in[3];
    const float* Aw   = (const float*)d_in[4];
    const float* As   = (const float*)d_in[5];
    const float* Bw   = (const float*)d_in[6];
    const float* Ew   = (const float*)d_in[7];
    const float* hf1  = (const float*)d_in[8];
    const float* hf2  = (const float*)d_in[9];
    char* ws    = (char*)d_ws;
    float* Xout = (float*)d_out;
    float* Yout = Xout + XTOT;

    prep_kernel<<<dim3(160), dim3(128), 0, stream>>>(Aw, As, hf1, hf2, Bw, Ew, ws);
    sq_kernel<<<dim3(1), dim3(256), 0, stream>>>(ws);
    prod_kernel<<<dim3(16), dim3(256), 0, stream>>>(ws);

    // K1: fused MLP + local scans -> XL (f16 RNE) + F (f32)
    fused_local<<<dim3(NCH * 64), dim3(256), 0, stream>>>(Mfl, DTi, Din, ws);
    // K2: carry propagation -> Init (f32)
    carry_kernel<<<dim3(64), dim3(64), 0, stream>>>(x_in, ws);
    // K3': parallel correction GEMM -> X, Y
    correct_kernel<<<dim3(16 * 64), dim3(256), 0, stream>>>(ws, Xout, Yout);
}

// Round 14
// 618.181 us; speedup vs baseline: 1.1722x; 1.1722x over previous
//
#include <hip/hip_runtime.h>

typedef _Float16 h4 __attribute__((ext_vector_type(4)));
typedef _Float16 h8 __attribute__((ext_vector_type(8)));
typedef __fp16 g2 __attribute__((ext_vector_type(2)));
typedef float f4 __attribute__((ext_vector_type(4)));

#define MFMA16(a, b, c) __builtin_amdgcn_mfma_f32_16x16x32_f16((a), (b), (c), 0, 0, 0)

static constexpr int TT  = 1024;
static constexpr int BS  = 1024;
static constexpr int LCH = 16;   // chunk length
static constexpr int NCH = 64;   // chunks
static constexpr size_t XTOT = (size_t)TT * BS * 128;

// workspace byte offsets
static constexpr size_t WS_WT16 = 0;       // 128x128 f16 : W_eff^T (S row-major)
static constexpr size_t WS_HF1  = 32768;
static constexpr size_t WS_HF2  = 49152;
static constexpr size_t WS_BW   = 65536;
static constexpr size_t WS_EW   = 81920;
static constexpr size_t WS_FACT = 90112;   // 8 x 16384 f16: T1,U1,T2,U2,T4,U4,T8,U8
static constexpr size_t WS_POW  = 352256;  // 16 x 16384 f16: (W^p)^T, p=1..16
static constexpr size_t WS_F    = 876544;                               // NCH f32 slots
static constexpr size_t WS_INIT = WS_F + (size_t)NCH * BS * 128 * 4;    // NCH f32 slots
static constexpr size_t WS_XL   = WS_INIT + (size_t)NCH * BS * 128 * 4; // T*B*128 f16

template <typename T>
__device__ inline T ntload(const T* p) { return __builtin_nontemporal_load(p); }

__device__ inline h4 pk4(f4 a) {  // RTZ packed (MLP path only)
    g2 p0 = __builtin_amdgcn_cvt_pkrtz(a[0], a[1]);
    g2 p1 = __builtin_amdgcn_cvt_pkrtz(a[2], a[3]);
    h4 r;
    r[0] = (_Float16)p0[0]; r[1] = (_Float16)p0[1];
    r[2] = (_Float16)p1[0]; r[3] = (_Float16)p1[1];
    return r;
}
__device__ inline f4 relu4(f4 a) {
    f4 r;
#pragma unroll
    for (int j = 0; j < 4; ++j) r[j] = fmaxf(a[j], 0.f);
    return r;
}

// ---------------------------------------------------------------------------
// prep: W_eff (softmax+scale, stored transposed = S row-major) + f16 weights
// ---------------------------------------------------------------------------
__global__ void prep_kernel(const float* __restrict__ Aw, const float* __restrict__ As,
                            const float* __restrict__ hf1, const float* __restrict__ hf2,
                            const float* __restrict__ Bw, const float* __restrict__ Ew,
                            char* __restrict__ ws)
{
    const int tid = threadIdx.x;  // 128
    const int bid = blockIdx.x;   // 160
    if (bid < 128) {
        __shared__ float red[128];
        const int n = bid;
        const float a = Aw[n * 128 + tid];
        red[tid] = a;
        __syncthreads();
        for (int s = 64; s > 0; s >>= 1) {
            if (tid < s) red[tid] = fmaxf(red[tid], red[tid + s]);
            __syncthreads();
        }
        const float mx = red[0];
        __syncthreads();
        const float e = expf(a - mx);
        red[tid] = e;
        __syncthreads();
        for (int s = 64; s > 0; s >>= 1) {
            if (tid < s) red[tid] += red[tid + s];
            __syncthreads();
        }
        const float sm  = e / red[0];
        const float asv = As[n * 128 + tid];
        const float sc  = 1.0f - 0.1f * (1.0f / (1.0f + expf(-asv)));
        ((_Float16*)(ws + WS_WT16))[n * 128 + tid] = (_Float16)(sc * sm);
    } else {
        const int b2 = bid - 128;  // 32 blocks
        for (int i = b2 * 128 + tid; i < 8192; i += 32 * 128) {
            ((_Float16*)(ws + WS_HF1))[i] = (_Float16)hf1[i];
            ((_Float16*)(ws + WS_HF2))[i] = (_Float16)hf2[i];
            ((_Float16*)(ws + WS_BW))[i]  = (_Float16)Bw[i];
            if (i < 4096) ((_Float16*)(ws + WS_EW))[i] = (_Float16)Ew[i];
        }
    }
}

// ---------------------------------------------------------------------------
// sq_kernel: dual-chain squarings -> FACT pairs (T,U) for W^{1,2,4,8}.
// ---------------------------------------------------------------------------
__global__ void sq_kernel(char* __restrict__ ws)
{
    const int tid  = threadIdx.x;
    const int lane = tid & 63;
    const int w    = tid >> 6;
    const int cl   = lane & 15;
    const int gq   = lane >> 4;
    constexpr int LDP = 136;

    __shared__ __align__(16) _Float16 G[2][128 * LDP];
    __shared__ __align__(16) _Float16 H[2][128 * LDP];

    const _Float16* Wt16 = (const _Float16*)(ws + WS_WT16);
    _Float16* FACT       = (_Float16*)(ws + WS_FACT);

    for (int i = tid; i < 2048; i += 256) {
        h8 v = *(const h8*)&Wt16[i * 8];
        *(h8*)&G[0][(i >> 4) * LDP + (i & 15) * 8] = v;
        *(h8*)&FACT[i * 8] = v;  // T1
    }
    __syncthreads();
    for (int i = tid; i < 16384; i += 256) {
        const int r = i >> 7, cc = i & 127;
        H[0][cc * LDP + r] = G[0][r * LDP + cc];
    }
    __syncthreads();
    for (int i = tid; i < 2048; i += 256)  // U1
        *(h8*)&FACT[16384 + i * 8] = *(const h8*)&H[0][(i >> 4) * LDP + (i & 15) * 8];

    int cur = 0;
    for (int s = 0; s < 3; ++s) {  // W^2, W^4, W^8
        const _Float16* Gs = G[cur];
        const _Float16* Hs = H[cur];
        _Float16* Gd = G[cur ^ 1];
        _Float16* Hd = H[cur ^ 1];
        f4 aG[8][2], aH[8][2];
#pragma unroll
        for (int mt = 0; mt < 8; ++mt)
#pragma unroll
            for (int nt = 0; nt < 2; ++nt) { aG[mt][nt] = f4{}; aH[mt][nt] = f4{}; }
#pragma unroll
        for (int kk = 0; kk < 4; ++kk) {
            h8 bG0 = *(const h8*)&Hs[((w * 2 + 0) * 16 + cl) * LDP + kk * 32 + gq * 8];
            h8 bG1 = *(const h8*)&Hs[((w * 2 + 1) * 16 + cl) * LDP + kk * 32 + gq * 8];
            h8 bH0 = *(const h8*)&Gs[((w * 2 + 0) * 16 + cl) * LDP + kk * 32 + gq * 8];
            h8 bH1 = *(const h8*)&Gs[((w * 2 + 1) * 16 + cl) * LDP + kk * 32 + gq * 8];
#pragma unroll
            for (int mt = 0; mt < 8; ++mt) {
                h8 ag = *(const h8*)&Gs[(mt * 16 + cl) * LDP + kk * 32 + gq * 8];
                h8 ah = *(const h8*)&Hs[(mt * 16 + cl) * LDP + kk * 32 + gq * 8];
                aG[mt][0] = MFMA16(ag, bG0, aG[mt][0]);
                aG[mt][1] = MFMA16(ag, bG1, aG[mt][1]);
                aH[mt][0] = MFMA16(ah, bH0, aH[mt][0]);
                aH[mt][1] = MFMA16(ah, bH1, aH[mt][1]);
            }
        }
        __syncthreads();
#pragma unroll
        for (int mt = 0; mt < 8; ++mt)
#pragma unroll
            for (int nt = 0; nt < 2; ++nt) {
                h4 hg, hh;
#pragma unroll
                for (int r = 0; r < 4; ++r) {
                    hg[r] = (_Float16)aG[mt][nt][r];
                    hh[r] = (_Float16)aH[mt][nt][r];
                }
                const int col  = (w * 2 + nt) * 16 + cl;
                const int rowb = mt * 16 + gq * 4;
                *(h4*)&Hd[col * LDP + rowb] = hg;   // U_{2f}
                *(h4*)&Gd[col * LDP + rowb] = hh;   // T_{2f}
            }
        __syncthreads();
        cur ^= 1;
        const size_t toff = (size_t)(2 * (s + 1)) * 16384;       // T_{2^{s+1}}
        for (int i = tid; i < 2048; i += 256) {
            *(h8*)&FACT[toff + i * 8] =
                *(const h8*)&G[cur][(i >> 4) * LDP + (i & 15) * 8];
            *(h8*)&FACT[toff + 16384 + i * 8] =
                *(const h8*)&H[cur][(i >> 4) * LDP + (i & 15) * 8];
        }
        __syncthreads();
    }
}

// ---------------------------------------------------------------------------
// prod_kernel: block p-1 computes POW[p-1] = T_p = (W^p)^T from binary
// factors (<=3 chained dual products; powers of W commute).
// ---------------------------------------------------------------------------
__global__ void prod_kernel(char* __restrict__ ws)
{
    const int tid  = threadIdx.x;
    const int lane = tid & 63;
    const int w    = tid >> 6;
    const int cl   = lane & 15;
    const int gq   = lane >> 4;
    const int p    = blockIdx.x + 1;  // 1..16
    constexpr int LDP = 136;

    const _Float16* FACT = (const _Float16*)(ws + WS_FACT);
    _Float16* POW        = (_Float16*)(ws + WS_POW);

    int fl[4], nf = 0;
    if (p == 16) { fl[0] = 8; fl[1] = 8; nf = 2; }
    else { for (int b = 8; b >= 1; b >>= 1) if (p & b) fl[nf++] = b; }

    if (nf == 1) {
        const int fi = (p == 1) ? 0 : (p == 2) ? 1 : (p == 4) ? 2 : 3;
        for (int i = tid; i < 2048; i += 256)
            *(h8*)&POW[(size_t)(p - 1) * 16384 + i * 8] =
                *(const h8*)&FACT[(size_t)(2 * fi) * 16384 + i * 8];
        return;
    }

    __shared__ __align__(16) _Float16 TA[128 * LDP], UA[128 * LDP];
    __shared__ __align__(16) _Float16 TB[128 * LDP], UB[128 * LDP];

    auto fidx = [](int f) { return (f == 1) ? 0 : (f == 2) ? 1 : (f == 4) ? 2 : 3; };
    auto loadpair = [&](int f, _Float16* T, _Float16* U) {
        const size_t toff = (size_t)(2 * fidx(f)) * 16384;
        for (int i = tid; i < 2048; i += 256) {
            *(h8*)&T[(i >> 4) * LDP + (i & 15) * 8] = *(const h8*)&FACT[toff + i * 8];
            *(h8*)&U[(i >> 4) * LDP + (i & 15) * 8] =
                *(const h8*)&FACT[toff + 16384 + i * 8];
        }
    };

    loadpair(fl[0], TA, UA);
    _Float16 *Tc = TA, *Uc = UA, *To = TB, *Uo = UB;

    for (int j = 1; j < nf; ++j) {
        loadpair(fl[j], To, Uo);
        __syncthreads();
        f4 aA[8][2], aB[8][2];
#pragma unroll
        for (int mt = 0; mt < 8; ++mt)
#pragma unroll
            for (int nt = 0; nt < 2; ++nt) { aA[mt][nt] = f4{}; aB[mt][nt] = f4{}; }
#pragma unroll
        for (int kk = 0; kk < 4; ++kk) {
            h8 bA0 = *(const h8*)&Uc[((w * 2 + 0) * 16 + cl) * LDP + kk * 32 + gq * 8];
            h8 bA1 = *(const h8*)&Uc[((w * 2 + 1) * 16 + cl) * LDP + kk * 32 + gq * 8];
            h8 bB0 = *(const h8*)&To[((w * 2 + 0) * 16 + cl) * LDP + kk * 32 + gq * 8];
            h8 bB1 = *(const h8*)&To[((w * 2 + 1) * 16 + cl) * LDP + kk * 32 + gq * 8];
#pragma unroll
            for (int mt = 0; mt < 8; ++mt) {
                h8 aT = *(const h8*)&To[(mt * 16 + cl) * LDP + kk * 32 + gq * 8];
                h8 aU = *(const h8*)&Uc[(mt * 16 + cl) * LDP + kk * 32 + gq * 8];
                aA[mt][0] = MFMA16(aT, bA0, aA[mt][0]);
                aA[mt][1] = MFMA16(aT, bA1, aA[mt][1]);
                aB[mt][0] = MFMA16(aU, bB0, aB[mt][0]);
                aB[mt][1] = MFMA16(aU, bB1, aB[mt][1]);
            }
        }
        __syncthreads();
#pragma unroll
        for (int mt = 0; mt < 8; ++mt)
#pragma unroll
            for (int nt = 0; nt < 2; ++nt) {
                h4 hA, hB;
#pragma unroll
                for (int r = 0; r < 4; ++r) {
                    hA[r] = (_Float16)aA[mt][nt][r];
                    hB[r] = (_Float16)aB[mt][nt][r];
                }
                const int col  = (w * 2 + nt) * 16 + cl;
                const int rowb = mt * 16 + gq * 4;
                *(h4*)&Uo[col * LDP + rowb] = hA;
                *(h4*)&To[col * LDP + rowb] = hB;
            }
        __syncthreads();
        _Float16* t;
        t = Tc; Tc = To; To = t;
        t = Uc; Uc = Uo; Uo = t;
    }
    for (int i = tid; i < 2048; i += 256)
        *(h8*)&POW[(size_t)(p - 1) * 16384 + i * 8] =
            *(const h8*)&Tc[(i >> 4) * LDP + (i & 15) * 8];
}

// ---------------------------------------------------------------------------
// K1: fused MLP + LOCAL scan (zero init), chunk=16 t x 16 b, 4 waves n-split.
// Streams Xl (f16 RNE, fragment order); F[c] (f32) at k=15.
// ---------------------------------------------------------------------------
__global__ __launch_bounds__(256, 1)
void fused_local(const float* __restrict__ Mfl, const float* __restrict__ DTi,
                 const float* __restrict__ Din, char* __restrict__ ws)
{
    const int tid  = threadIdx.x;
    const int lane = tid & 63;
    const int w    = tid >> 6;
    const int cl   = lane & 15;
    const int gq   = lane >> 4;
    const int bt   = blockIdx.x & 63;
    const int c    = blockIdx.x >> 6;   // 0..63
    const int b0   = bt * 16;

    const _Float16* Hf1  = (const _Float16*)(ws + WS_HF1);
    const _Float16* Hf2  = (const _Float16*)(ws + WS_HF2);
    const _Float16* Bw16 = (const _Float16*)(ws + WS_BW);
    const _Float16* Ew16 = (const _Float16*)(ws + WS_EW);
    const _Float16* Wt16 = (const _Float16*)(ws + WS_WT16);
    float* Fbuf          = (float*)(ws + WS_F);
    _Float16* XL         = (_Float16*)(ws + WS_XL);

    __shared__ __align__(16) _Float16 mds[4][16 * 64];
    __shared__ __align__(16) _Float16 dts[4][16 * 32];
    __shared__ __align__(16) _Float16 hs[4][16 * 128];
    __shared__ __align__(16) _Float16 us[4][16 * 64];
    __shared__ __align__(16) _Float16 xsh[2][16 * 128];

    h8 hf1f[2][2], bwf[2][2], ewf[2], hf2f[4];
#pragma unroll
    for (int nt = 0; nt < 2; ++nt) {
        const int ng = w * 32 + nt * 16 + cl;
#pragma unroll
        for (int kk = 0; kk < 2; ++kk) {
            hf1f[nt][kk] = *(const h8*)&Hf1[ng * 64 + kk * 32 + gq * 8];
            bwf[nt][kk]  = *(const h8*)&Bw16[ng * 64 + kk * 32 + gq * 8];
        }
        ewf[nt] = *(const h8*)&Ew16[ng * 32 + gq * 8];
    }
    {
        const int ng = w * 16 + cl;
#pragma unroll
        for (int kk = 0; kk < 4; ++kk)
            hf2f[kk] = *(const h8*)&Hf2[ng * 128 + kk * 32 + gq * 8];
    }
    h8 wfp[2][4];
#pragma unroll
    for (int nt = 0; nt < 2; ++nt)
#pragma unroll
        for (int kt = 0; kt < 4; ++kt)
            wfp[nt][kt] =
                *(const h8*)&Wt16[(w * 32 + nt * 16 + cl) * 128 + kt * 32 + gq * 8];

    {
        h8 z = {};
        *(h8*)&xsh[0][tid * 8] = z;
    }

    const int qrow = (tid & 127) >> 3;
    const int qc4  = (tid & 7) * 4;
    f4 pm[4], pd[4];
    auto GLOAD = [&](int g) {
#pragma unroll
        for (int s = 0; s < 4; ++s) {
            const size_t t  = (size_t)c * LCH + g * 4 + s;
            const size_t rb = (t * BS + b0 + qrow) * 32 + qc4;
            pm[s] = (tid < 128) ? ntload((const f4*)&Mfl[rb]) : ntload((const f4*)&DTi[rb]);
            if (tid < 128) pd[s] = ntload((const f4*)&Din[rb]);
        }
    };
    GLOAD(0);

    _Float16* xcur = xsh[0];
    _Float16* xnxt = xsh[1];

    for (int g = 0; g < 4; ++g) {
#pragma unroll
        for (int s = 0; s < 4; ++s) {
            const int col = (tid < 128) ? qc4 : (32 + qc4);
            h4 hv = pk4(pm[s]);
            *(h4*)&mds[s][qrow * 64 + (((col >> 3) ^ (qrow & 7)) * 8) + (col & 7)] = hv;
            if (tid < 128) {
                h4 h2v = pk4(pd[s]);
                *(h4*)&dts[s][qrow * 32 + (((qc4 >> 3) ^ (qrow & 3)) * 8) + (qc4 & 7)] = h2v;
            }
        }
        if (g < 3) GLOAD(g + 1);
        __syncthreads();

        // G1
#pragma unroll
        for (int s = 0; s < 4; ++s) {
            f4 ha0 = {}, ha1 = {};
#pragma unroll
            for (int kk = 0; kk < 2; ++kk) {
                h8 a = *(const h8*)&mds[s][cl * 64 + (((kk * 4 + gq) ^ (cl & 7)) * 8)];
                ha0 = MFMA16(hf1f[0][kk], a, ha0);
                ha1 = MFMA16(hf1f[1][kk], a, ha1);
            }
#pragma unroll
            for (int nt = 0; nt < 2; ++nt) {
                const int nb8 = w * 4 + nt * 2 + (gq >> 1);
                h4 hv = pk4(relu4(nt ? ha1 : ha0));
                *(h4*)&hs[s][cl * 128 + ((nb8 ^ cl) & 15) * 8 + (gq & 1) * 4] = hv;
            }
        }
        __syncthreads();

        // G2
#pragma unroll
        for (int s = 0; s < 4; ++s) {
            f4 ua = {};
#pragma unroll
            for (int kt = 0; kt < 4; ++kt) {
                h8 a = *(const h8*)&hs[s][cl * 128 + (((kt * 4 + gq) ^ cl) & 15) * 8];
                ua = MFMA16(hf2f[kt], a, ua);
            }
            const int ub8 = w * 2 + (gq >> 1);
            h4 uv = pk4(relu4(ua));
            *(h4*)&us[s][cl * 64 + ((ub8 ^ (cl & 7)) & 7) * 8 + (gq & 1) * 4] = uv;
        }
        __syncthreads();

        // G3 -> dv (h4 regs)
        h4 dv0[4], dv1[4];
#pragma unroll
        for (int s = 0; s < 4; ++s) {
            f4 a20 = {}, a21 = {};
#pragma unroll
            for (int kk = 0; kk < 2; ++kk) {
                h8 a = *(const h8*)&us[s][cl * 64 + (((kk * 4 + gq) ^ (cl & 7)) & 7) * 8];
                a20 = MFMA16(bwf[0][kk], a, a20);
                a21 = MFMA16(bwf[1][kk], a, a21);
            }
            {
                h8 ad = *(const h8*)&dts[s][cl * 32 + ((gq ^ (cl & 3)) * 8)];
                a20 = MFMA16(ewf[0], ad, a20);
                a21 = MFMA16(ewf[1], ad, a21);
            }
            dv0[s] = pk4(a20);
            dv1[s] = pk4(a21);
        }

        // 4 local-scan steps
#pragma unroll
        for (int s = 0; s < 4; ++s) {
            h8 xf[4];
#pragma unroll
            for (int kt = 0; kt < 4; ++kt)
                xf[kt] = *(const h8*)&xcur[cl * 128 + (((kt * 4 + gq) ^ cl) & 15) * 8];
            f4 acc0, acc1;
#pragma unroll
            for (int r = 0; r < 4; ++r) {
                acc0[r] = (float)dv0[s][r];
                acc1[r] = (float)dv1[s][r];
            }
#pragma unroll
            for (int kt = 0; kt < 4; ++kt) {
                acc0 = MFMA16(wfp[0][kt], xf[kt], acc0);
                acc1 = MFMA16(wfp[1][kt], xf[kt], acc1);
            }

            // stream Xl (f16 RNE, fragment order)
            {
                const size_t t = (size_t)c * LCH + g * 4 + s;
                h8 o;
#pragma unroll
                for (int r = 0; r < 4; ++r) {
                    o[r]     = (_Float16)acc0[r];
                    o[4 + r] = (_Float16)acc1[r];
                }
                *(h8*)&XL[((t * 64 + bt) * 256 + tid) * 8] = o;
            }

            const bool last = (g == 3) && (s == 3);
            if (last) {
                float* fp = &Fbuf[((size_t)c * BS + b0 + cl) * 128 + w * 32 + gq * 4];
                *(f4*)fp = acc0;
                *(f4*)(fp + 16) = acc1;
            } else {
#pragma unroll
                for (int nt = 0; nt < 2; ++nt) {
                    h4 hv;
#pragma unroll
                    for (int r = 0; r < 4; ++r) hv[r] = (_Float16)(nt ? acc1[r] : acc0[r]);
                    const int nb8 = w * 4 + nt * 2 + (gq >> 1);
                    *(h4*)&xnxt[cl * 128 + ((nb8 ^ cl) & 15) * 8 + (gq & 1) * 4] = hv;
                }
                __syncthreads();
                _Float16* tmp = xcur; xcur = xnxt; xnxt = tmp;
            }
        }
    }
}

// ---------------------------------------------------------------------------
// K2: carry Init[cc] = Init[cc-1] @ W^16 + F[cc-1]; Init kept f32.
// ---------------------------------------------------------------------------
__global__ __launch_bounds__(64, 1)
void carry_kernel(const float* __restrict__ x0, char* __restrict__ ws)
{
    const int lane = threadIdx.x;
    const int cl = lane & 15, gq = lane >> 4;
    const int b0 = blockIdx.x * 16;

    const _Float16* W16 = (const _Float16*)(ws + WS_POW) + (size_t)15 * 16384;
    const float* Fbuf   = (const float*)(ws + WS_F);
    float* Init         = (float*)(ws + WS_INIT);

    __shared__ __align__(16) _Float16 tbuf[16 * 128];

    h8 wf[8][4];
#pragma unroll
    for (int nt = 0; nt < 8; ++nt)
#pragma unroll
        for (int kt = 0; kt < 4; ++kt)
            wf[nt][kt] = *(const h8*)&W16[(nt * 16 + cl) * 128 + kt * 32 + gq * 8];

    h8 xf[4];
    {
        f4 iv[8];
#pragma unroll
        for (int nt = 0; nt < 8; ++nt)
            iv[nt] = *(const f4*)&x0[(size_t)(b0 + cl) * 128 + nt * 16 + gq * 4];
#pragma unroll
        for (int nt = 0; nt < 8; ++nt)
            *(f4*)&Init[(size_t)(b0 + cl) * 128 + nt * 16 + gq * 4] = iv[nt];
#pragma unroll
        for (int nt = 0; nt < 8; ++nt) {
            h4 hv;
#pragma unroll
            for (int r = 0; r < 4; ++r) hv[r] = (_Float16)iv[nt][r];
            *(h4*)&tbuf[cl * 128 + (((nt * 2 + (gq >> 1)) ^ cl) & 15) * 8 + (gq & 1) * 4] = hv;
        }
#pragma unroll
        for (int kt = 0; kt < 4; ++kt)
            xf[kt] = *(const h8*)&tbuf[cl * 128 + (((kt * 4 + gq) ^ cl) & 15) * 8];
    }

    for (int cc = 1; cc < NCH; ++cc) {
        f4 acc[8];
#pragma unroll
        for (int nt = 0; nt < 8; ++nt)
            acc[nt] = *(const f4*)&Fbuf[((size_t)(cc - 1) * BS + b0 + cl) * 128 + nt * 16 + gq * 4];
#pragma unroll
        for (int kt = 0; kt < 4; ++kt)
#pragma unroll
            for (int nt = 0; nt < 8; ++nt)
                acc[nt] = MFMA16(wf[kt == 0 ? nt : nt][kt], xf[kt], acc[nt]);
#pragma unroll
        for (int nt = 0; nt < 8; ++nt)
            *(f4*)&Init[((size_t)cc * BS + b0 + cl) * 128 + nt * 16 + gq * 4] = acc[nt];
        if (cc < NCH - 1) {
#pragma unroll
            for (int nt = 0; nt < 8; ++nt) {
                h4 hv;
#pragma unroll
                for (int r = 0; r < 4; ++r) hv[r] = (_Float16)acc[nt][r];
                *(h4*)&tbuf[cl * 128 + (((nt * 2 + (gq >> 1)) ^ cl) & 15) * 8 + (gq & 1) * 4] = hv;
            }
#pragma unroll
            for (int kt = 0; kt < 4; ++kt)
                xf[kt] = *(const h8*)&tbuf[cl * 128 + (((kt * 4 + gq) ^ cl) & 15) * 8];
        }
    }
}

// ---------------------------------------------------------------------------
// K3': correction with DENSE stores. Block (half, k, bt): for c in half-range,
// X[c*16+k] = Xl + Init_c @ W^{k+1}. acc staged to LDS (XOR-swizzled),
// then cooperatively streamed out tid-linear (4 KB/instr, full lines).
// ---------------------------------------------------------------------------
__global__ __launch_bounds__(256, 2)
void correct_kernel(char* __restrict__ ws, float* __restrict__ Xout,
                    float* __restrict__ Yout)
{
    const int tid  = threadIdx.x;
    const int lane = tid & 63;
    const int w    = tid >> 6;
    const int cl   = lane & 15;
    const int gq   = lane >> 4;
    const int bid  = blockIdx.x;          // 2048 blocks
    const int half = bid >> 10;           // 0..1
    const int k    = (bid >> 6) & 15;     // 0..15
    const int bt   = bid & 63;
    const int b0   = bt * 16;
    const int c0   = half * 32;

    const _Float16* Tk  = (const _Float16*)(ws + WS_POW) + (size_t)k * 16384;
    const float* Init   = (const float*)(ws + WS_INIT);
    const _Float16* XL  = (const _Float16*)(ws + WS_XL);

    __shared__ __align__(16) f4 stage[2][16 * 32];  // 2 x 8 KB

    h8 wfp[2][4];
#pragma unroll
    for (int nt = 0; nt < 2; ++nt)
#pragma unroll
        for (int kt = 0; kt < 4; ++kt)
            wfp[nt][kt] =
                *(const h8*)&Tk[(w * 32 + nt * 16 + cl) * 128 + kt * 32 + gq * 8];

    auto LOADC = [&](int c, h8* xf, h8& xl) {
        const float* ib = &Init[((size_t)c * BS + b0 + cl) * 128 + gq * 8];
#pragma unroll
        for (int kt = 0; kt < 4; ++kt) {
            f4 v0 = *(const f4*)&ib[kt * 32];
            f4 v1 = *(const f4*)&ib[kt * 32 + 4];
            h8 x;
#pragma unroll
            for (int r = 0; r < 4; ++r) {
                x[r]     = (_Float16)v0[r];
                x[4 + r] = (_Float16)v1[r];
            }
            xf[kt] = x;
        }
        const size_t t = (size_t)c * LCH + k;
        xl = *(const h8*)&XL[((t * 64 + bt) * 256 + tid) * 8];
    };

#define CSTEP(C, P, XF, XLR)                                                         \
    {                                                                                \
        f4 acc0, acc1;                                                               \
        _Pragma("unroll") for (int r = 0; r < 4; ++r) {                              \
            acc0[r] = (float)XLR[r];                                                 \
            acc1[r] = (float)XLR[4 + r];                                             \
        }                                                                            \
        _Pragma("unroll") for (int kt = 0; kt < 4; ++kt) {                           \
            acc0 = MFMA16(wfp[0][kt], XF[kt], acc0);                                 \
            acc1 = MFMA16(wfp[1][kt], XF[kt], acc1);                                 \
        }                                                                            \
        if ((C) + 2 < c0 + 32) LOADC((C) + 2, XF, XLR);                              \
        stage[P][cl * 32 + ((w * 8 + gq) ^ (cl & 7))]     = acc0;                    \
        stage[P][cl * 32 + ((w * 8 + gq + 4) ^ (cl & 7))] = acc1;                    \
        __syncthreads();                                                             \
        const size_t t     = (size_t)(C) * LCH + k;                                  \
        const size_t xbase = (t * BS + b0) * 128;                                    \
        _Pragma("unroll") for (int p2 = 0; p2 < 2; ++p2) {                           \
            const int f   = p2 * 256 + tid;                                          \
            const int row = f >> 5, j = f & 31;                                      \
            f4 v = stage[P][row * 32 + (j ^ (row & 7))];                              \
            __builtin_nontemporal_store(v, (f4*)&Xout[xbase + (size_t)f * 4]);       \
            if (j == 31)                                                             \
                __builtin_nontemporal_store(v[3], &Yout[t * BS + b0 + row]);         \
        }                                                                            \
    }

    h8 xfA[4], xfB[4], xlA, xlB;
    LOADC(c0, xfA, xlA);
    LOADC(c0 + 1, xfB, xlB);
    for (int c = c0; c < c0 + 32; c += 2) {
        CSTEP(c, 0, xfA, xlA);
        CSTEP(c + 1, 1, xfB, xlB);
    }
#undef CSTEP
}

// ---------------------------------------------------------------------------
extern "C" void kernel_launch(void* const* d_in, const int* in_sizes, int n_in,
                              void* d_out, int out_size, void* d_ws, size_t ws_size,
                              hipStream_t stream)
{
    const float* x_in = (const float*)d_in[0];
    const float* Mfl  = (const float*)d_in[1];
    const float* DTi  = (const float*)d_in[2];
    const float* Din  = (const float*)d_in[3];
    const float* Aw   = (const float*)d_in[4];
    const float* As   = (const float*)d_in[5];
    const float* Bw   = (const float*)d_in[6];
    const float* Ew   = (const float*)d_in[7];
    const float* hf1  = (const float*)d_in[8];
    const float* hf2  = (const float*)d_in[9];
    char* ws    = (char*)d_ws;
    float* Xout = (float*)d_out;
    float* Yout = Xout + XTOT;

    prep_kernel<<<dim3(160), dim3(128), 0, stream>>>(Aw, As, hf1, hf2, Bw, Ew, ws);
    sq_kernel<<<dim3(1), dim3(256), 0, stream>>>(ws);
    prod_kernel<<<dim3(16), dim3(256), 0, stream>>>(ws);

    // K1: fused MLP + local scans -> XL (f16 RNE) + F (f32)
    fused_local<<<dim3(NCH * 64), dim3(256), 0, stream>>>(Mfl, DTi, Din, ws);
    // K2: carry propagation -> Init (f32)
    carry_kernel<<<dim3(64), dim3(64), 0, stream>>>(x_in, ws);
    // K3': parallel correction GEMM with dense stores -> X, Y
    correct_kernel<<<dim3(2048), dim3(256), 0, stream>>>(ws, Xout, Yout);
}

// Round 15
// 418.505 us; speedup vs baseline: 1.7315x; 1.4771x over previous
//
#include <hip/hip_runtime.h>

typedef _Float16 h4 __attribute__((ext_vector_type(4)));
typedef _Float16 h8 __attribute__((ext_vector_type(8)));
typedef __fp16 g2 __attribute__((ext_vector_type(2)));
typedef float f4 __attribute__((ext_vector_type(4)));

#define MFMA16(a, b, c) __builtin_amdgcn_mfma_f32_16x16x32_f16((a), (b), (c), 0, 0, 0)

static constexpr int TT  = 1024;
static constexpr int BS  = 1024;
static constexpr int LCH = 32;   // chunk length
static constexpr int NCH = 32;   // chunks
static constexpr size_t XTOT = (size_t)TT * BS * 128;

// workspace byte offsets
static constexpr size_t WS_WT16 = 0;       // 128x128 f16 : W_eff^T (S row-major)
static constexpr size_t WS_HF1  = 32768;
static constexpr size_t WS_HF2  = 49152;
static constexpr size_t WS_BW   = 65536;
static constexpr size_t WS_EW   = 81920;
static constexpr size_t WS_W32  = 90112;   // 128x128 f16 : (W^32)^T layout
static constexpr size_t WS_F    = 131072;                              // NCH f32 slots
static constexpr size_t WS_INIT = WS_F + (size_t)NCH * BS * 128 * 4;   // NCH f32 slots

template <typename T>
__device__ inline T ntload(const T* p) { return __builtin_nontemporal_load(p); }

__device__ inline h4 pk4(f4 a) {  // RTZ packed (MLP path only)
    g2 p0 = __builtin_amdgcn_cvt_pkrtz(a[0], a[1]);
    g2 p1 = __builtin_amdgcn_cvt_pkrtz(a[2], a[3]);
    h4 r;
    r[0] = (_Float16)p0[0]; r[1] = (_Float16)p0[1];
    r[2] = (_Float16)p1[0]; r[3] = (_Float16)p1[1];
    return r;
}
__device__ inline f4 relu4(f4 a) {
    f4 r;
#pragma unroll
    for (int j = 0; j < 4; ++j) r[j] = fmaxf(a[j], 0.f);
    return r;
}

// ---------------------------------------------------------------------------
// prep: W_eff (softmax+scale, stored transposed = S row-major) + f16 weights
// ---------------------------------------------------------------------------
__global__ void prep_kernel(const float* __restrict__ Aw, const float* __restrict__ As,
                            const float* __restrict__ hf1, const float* __restrict__ hf2,
                            const float* __restrict__ Bw, const float* __restrict__ Ew,
                            char* __restrict__ ws)
{
    const int tid = threadIdx.x;  // 128
    const int bid = blockIdx.x;   // 160
    if (bid < 128) {
        __shared__ float red[128];
        const int n = bid;
        const float a = Aw[n * 128 + tid];
        red[tid] = a;
        __syncthreads();
        for (int s = 64; s > 0; s >>= 1) {
            if (tid < s) red[tid] = fmaxf(red[tid], red[tid + s]);
            __syncthreads();
        }
        const float mx = red[0];
        __syncthreads();
        const float e = expf(a - mx);
        red[tid] = e;
        __syncthreads();
        for (int s = 64; s > 0; s >>= 1) {
            if (tid < s) red[tid] += red[tid + s];
            __syncthreads();
        }
        const float sm  = e / red[0];
        const float asv = As[n * 128 + tid];
        const float sc  = 1.0f - 0.1f * (1.0f / (1.0f + expf(-asv)));
        ((_Float16*)(ws + WS_WT16))[n * 128 + tid] = (_Float16)(sc * sm);
    } else {
        const int b2 = bid - 128;  // 32 blocks
        for (int i = b2 * 128 + tid; i < 8192; i += 32 * 128) {
            ((_Float16*)(ws + WS_HF1))[i] = (_Float16)hf1[i];
            ((_Float16*)(ws + WS_HF2))[i] = (_Float16)hf2[i];
            ((_Float16*)(ws + WS_BW))[i]  = (_Float16)Bw[i];
            if (i < 4096) ((_Float16*)(ws + WS_EW))[i] = (_Float16)Ew[i];
        }
    }
}

// ---------------------------------------------------------------------------
// W^32 via 5 dual-chain squarings (verified): G=(W^T)^(2^s), H=G^T.
// ---------------------------------------------------------------------------
__global__ void w32_kernel(char* __restrict__ ws)
{
    const int tid  = threadIdx.x;
    const int lane = tid & 63;
    const int w    = tid >> 6;
    const int cl   = lane & 15;
    const int gq   = lane >> 4;
    constexpr int LDP = 136;

    __shared__ __align__(16) _Float16 G[2][128 * LDP];
    __shared__ __align__(16) _Float16 H[2][128 * LDP];

    const _Float16* Wt16 = (const _Float16*)(ws + WS_WT16);
    for (int i = tid; i < 2048; i += 256)
        *(h8*)&G[0][(i >> 4) * LDP + (i & 15) * 8] = *(const h8*)&Wt16[i * 8];
    __syncthreads();
    for (int i = tid; i < 16384; i += 256) {
        const int r = i >> 7, cc = i & 127;
        H[0][cc * LDP + r] = G[0][r * LDP + cc];
    }
    __syncthreads();

    int cur = 0;
    for (int s = 0; s < 5; ++s) {
        const _Float16* Gs = G[cur];
        const _Float16* Hs = H[cur];
        _Float16* Gd = G[cur ^ 1];
        _Float16* Hd = H[cur ^ 1];
        f4 aG[8][2], aH[8][2];
#pragma unroll
        for (int mt = 0; mt < 8; ++mt)
#pragma unroll
            for (int nt = 0; nt < 2; ++nt) { aG[mt][nt] = f4{}; aH[mt][nt] = f4{}; }
#pragma unroll
        for (int kk = 0; kk < 4; ++kk) {
            h8 bG0 = *(const h8*)&Hs[((w * 2 + 0) * 16 + cl) * LDP + kk * 32 + gq * 8];
            h8 bG1 = *(const h8*)&Hs[((w * 2 + 1) * 16 + cl) * LDP + kk * 32 + gq * 8];
            h8 bH0 = *(const h8*)&Gs[((w * 2 + 0) * 16 + cl) * LDP + kk * 32 + gq * 8];
            h8 bH1 = *(const h8*)&Gs[((w * 2 + 1) * 16 + cl) * LDP + kk * 32 + gq * 8];
#pragma unroll
            for (int mt = 0; mt < 8; ++mt) {
                h8 ag = *(const h8*)&Gs[(mt * 16 + cl) * LDP + kk * 32 + gq * 8];
                h8 ah = *(const h8*)&Hs[(mt * 16 + cl) * LDP + kk * 32 + gq * 8];
                aG[mt][0] = MFMA16(ag, bG0, aG[mt][0]);
                aG[mt][1] = MFMA16(ag, bG1, aG[mt][1]);
                aH[mt][0] = MFMA16(ah, bH0, aH[mt][0]);
                aH[mt][1] = MFMA16(ah, bH1, aH[mt][1]);
            }
        }
        __syncthreads();
#pragma unroll
        for (int mt = 0; mt < 8; ++mt)
#pragma unroll
            for (int nt = 0; nt < 2; ++nt) {
                h4 hg, hh;
#pragma unroll
                for (int r = 0; r < 4; ++r) {
                    hg[r] = (_Float16)aG[mt][nt][r];
                    hh[r] = (_Float16)aH[mt][nt][r];
                }
                const int col  = (w * 2 + nt) * 16 + cl;
                const int rowb = mt * 16 + gq * 4;
                *(h4*)&Hd[col * LDP + rowb] = hg;
                *(h4*)&Gd[col * LDP + rowb] = hh;
            }
        __syncthreads();
        cur ^= 1;
    }
    _Float16* W32 = (_Float16*)(ws + WS_W32);
    for (int i = tid; i < 2048; i += 256)
        *(h8*)&W32[i * 8] = *(const h8*)&G[cur][(i >> 4) * LDP + (i & 15) * 8];
}

// ---------------------------------------------------------------------------
// fused_scan (R11 structure + dense X-stores): block = one chunk (32 t) x 16 b,
// 4 waves n-split. FINAL=true additionally stages acc into a double-buffered
// XOR-swizzled LDS tile and streams it out tid-linear (4 KB/instr) after the
// step's existing barrier — replaces the 512B-stride scatter stores.
// ---------------------------------------------------------------------------
template <bool FINAL>
__global__ __launch_bounds__(256, 1)
void fused_scan(const float* __restrict__ Mfl, const float* __restrict__ DTi,
                const float* __restrict__ Din, char* __restrict__ ws,
                float* __restrict__ Xout, float* __restrict__ Yout)
{
    const int tid  = threadIdx.x;
    const int lane = tid & 63;
    const int w    = tid >> 6;
    const int cl   = lane & 15;
    const int gq   = lane >> 4;
    const int bt   = blockIdx.x & 63;
    const int c    = blockIdx.x >> 6;
    const int b0   = bt * 16;

    const _Float16* Hf1  = (const _Float16*)(ws + WS_HF1);
    const _Float16* Hf2  = (const _Float16*)(ws + WS_HF2);
    const _Float16* Bw16 = (const _Float16*)(ws + WS_BW);
    const _Float16* Ew16 = (const _Float16*)(ws + WS_EW);
    const _Float16* Wt16 = (const _Float16*)(ws + WS_WT16);
    float* Fbuf          = (float*)(ws + WS_F);
    const float* Init    = (const float*)(ws + WS_INIT);

    __shared__ __align__(16) _Float16 mds[4][16 * 64];   // 8 KB
    __shared__ __align__(16) _Float16 dts[4][16 * 32];   // 4 KB
    __shared__ __align__(16) _Float16 hs[4][16 * 128];   // 16 KB
    __shared__ __align__(16) _Float16 us[4][16 * 64];    // 8 KB
    __shared__ __align__(16) _Float16 xsh[2][16 * 128];  // 8 KB
    __shared__ __align__(16) f4 stage[FINAL ? 1024 : 1]; // 8 KB (FINAL only)

    // ---- MLP weight fragments (A-operands, n-split)
    h8 hf1f[2][2], bwf[2][2], ewf[2], hf2f[4];
#pragma unroll
    for (int nt = 0; nt < 2; ++nt) {
        const int ng = w * 32 + nt * 16 + cl;
#pragma unroll
        for (int kk = 0; kk < 2; ++kk) {
            hf1f[nt][kk] = *(const h8*)&Hf1[ng * 64 + kk * 32 + gq * 8];
            bwf[nt][kk]  = *(const h8*)&Bw16[ng * 64 + kk * 32 + gq * 8];
        }
        ewf[nt] = *(const h8*)&Ew16[ng * 32 + gq * 8];
    }
    {
        const int ng = w * 16 + cl;
#pragma unroll
        for (int kk = 0; kk < 4; ++kk)
            hf2f[kk] = *(const h8*)&Hf2[ng * 128 + kk * 32 + gq * 8];
    }
    // ---- scan W^T fragments, n-split
    h8 wfp[2][4];
#pragma unroll
    for (int nt = 0; nt < 2; ++nt)
#pragma unroll
        for (int kt = 0; kt < 4; ++kt)
            wfp[nt][kt] =
                *(const h8*)&Wt16[(w * 32 + nt * 16 + cl) * 128 + kt * 32 + gq * 8];

    // ---- state init into xsh[0]
    if constexpr (FINAL) {
        const int row = tid >> 4, c8 = tid & 15;
        const float* src = &Init[((size_t)c * BS + b0 + row) * 128 + c8 * 8];
        f4 v0 = *(const f4*)src, v1 = *(const f4*)(src + 4);
        h8 hv;
#pragma unroll
        for (int j = 0; j < 4; ++j) { hv[j] = (_Float16)v0[j]; hv[4 + j] = (_Float16)v1[j]; }
        *(h8*)&xsh[0][row * 128 + ((c8 ^ row) & 15) * 8] = hv;
    } else {
        h8 z = {};
        *(h8*)&xsh[0][tid * 8] = z;
    }

    // ---- input loads (group-ahead prefetch; converts decoupled to staging)
    const int qrow = (tid & 127) >> 3;
    const int qc4  = (tid & 7) * 4;
    f4 pm[4], pd[4];
    auto GLOAD = [&](int g) {
#pragma unroll
        for (int s = 0; s < 4; ++s) {
            const size_t t  = (size_t)c * LCH + g * 4 + s;
            const size_t rb = (t * BS + b0 + qrow) * 32 + qc4;
            pm[s] = (tid < 128) ? ntload((const f4*)&Mfl[rb]) : ntload((const f4*)&DTi[rb]);
            if (tid < 128) pd[s] = ntload((const f4*)&Din[rb]);
        }
    };
    GLOAD(0);

    _Float16* xcur = xsh[0];
    _Float16* xnxt = xsh[1];

    for (int g = 0; g < 8; ++g) {
        // ---- stage current group's inputs (f16, swizzled; pkrtz)
#pragma unroll
        for (int s = 0; s < 4; ++s) {
            const int col = (tid < 128) ? qc4 : (32 + qc4);
            h4 hv = pk4(pm[s]);
            *(h4*)&mds[s][qrow * 64 + (((col >> 3) ^ (qrow & 7)) * 8) + (col & 7)] = hv;
            if (tid < 128) {
                h4 h2v = pk4(pd[s]);
                *(h4*)&dts[s][qrow * 32 + (((qc4 >> 3) ^ (qrow & 3)) * 8) + (qc4 & 7)] = h2v;
            }
        }
        if (g < 7) GLOAD(g + 1);  // in flight across MLP+scan phases
        __syncthreads();

        // ---- G1: h^T = hf1 * md^T
#pragma unroll
        for (int s = 0; s < 4; ++s) {
            f4 ha0 = {}, ha1 = {};
#pragma unroll
            for (int kk = 0; kk < 2; ++kk) {
                h8 a = *(const h8*)&mds[s][cl * 64 + (((kk * 4 + gq) ^ (cl & 7)) * 8)];
                ha0 = MFMA16(hf1f[0][kk], a, ha0);
                ha1 = MFMA16(hf1f[1][kk], a, ha1);
            }
#pragma unroll
            for (int nt = 0; nt < 2; ++nt) {
                const int nb8 = w * 4 + nt * 2 + (gq >> 1);
                h4 hv = pk4(relu4(nt ? ha1 : ha0));
                *(h4*)&hs[s][cl * 128 + ((nb8 ^ cl) & 15) * 8 + (gq & 1) * 4] = hv;
            }
        }
        __syncthreads();

        // ---- G2: u^T = hf2 * h^T
#pragma unroll
        for (int s = 0; s < 4; ++s) {
            f4 ua = {};
#pragma unroll
            for (int kt = 0; kt < 4; ++kt) {
                h8 a = *(const h8*)&hs[s][cl * 128 + (((kt * 4 + gq) ^ cl) & 15) * 8];
                ua = MFMA16(hf2f[kt], a, ua);
            }
            const int ub8 = w * 2 + (gq >> 1);
            h4 uv = pk4(relu4(ua));
            *(h4*)&us[s][cl * 64 + ((ub8 ^ (cl & 7)) & 7) * 8 + (gq & 1) * 4] = uv;
        }
        __syncthreads();

        // ---- G3: drive^T = Bw*u^T + Ew*D^T -> h4 register frags
        h4 dv0[4], dv1[4];
#pragma unroll
        for (int s = 0; s < 4; ++s) {
            f4 a20 = {}, a21 = {};
#pragma unroll
            for (int kk = 0; kk < 2; ++kk) {
                h8 a = *(const h8*)&us[s][cl * 64 + (((kk * 4 + gq) ^ (cl & 7)) & 7) * 8];
                a20 = MFMA16(bwf[0][kk], a, a20);
                a21 = MFMA16(bwf[1][kk], a, a21);
            }
            {
                h8 ad = *(const h8*)&dts[s][cl * 32 + ((gq ^ (cl & 3)) * 8)];
                a20 = MFMA16(ewf[0], ad, a20);
                a21 = MFMA16(ewf[1], ad, a21);
            }
            dv0[s] = pk4(a20);
            dv1[s] = pk4(a21);
        }

        // ---- scan 4 steps (cross-wave state via xsh; dense X stores)
#pragma unroll
        for (int s = 0; s < 4; ++s) {
            h8 xf[4];
#pragma unroll
            for (int kt = 0; kt < 4; ++kt)
                xf[kt] = *(const h8*)&xcur[cl * 128 + (((kt * 4 + gq) ^ cl) & 15) * 8];
            f4 acc0, acc1;
#pragma unroll
            for (int r = 0; r < 4; ++r) {
                acc0[r] = (float)dv0[s][r];
                acc1[r] = (float)dv1[s][r];
            }
#pragma unroll
            for (int kt = 0; kt < 4; ++kt) {
                acc0 = MFMA16(wfp[0][kt], xf[kt], acc0);
                acc1 = MFMA16(wfp[1][kt], xf[kt], acc1);
            }

            const bool last = (g == 7) && (s == 3);

            if constexpr (FINAL) {
                // stage acc into swizzled LDS tile (verified R14 mapping)
                stage[(s & 1) * 512 + cl * 32 + ((w * 8 + gq) ^ (cl & 7))]     = acc0;
                stage[(s & 1) * 512 + cl * 32 + ((w * 8 + gq + 4) ^ (cl & 7))] = acc1;
            }
            if (!FINAL && last) {
                float* fp = &Fbuf[((size_t)c * BS + b0 + cl) * 128 + w * 32 + gq * 4];
                *(f4*)fp = acc0;
                *(f4*)(fp + 16) = acc1;
            }
            if (!last) {
                // RNE casts on the feedback path (numerical safety)
#pragma unroll
                for (int nt = 0; nt < 2; ++nt) {
                    h4 hv;
#pragma unroll
                    for (int r = 0; r < 4; ++r) hv[r] = (_Float16)(nt ? acc1[r] : acc0[r]);
                    const int nb8 = w * 4 + nt * 2 + (gq >> 1);
                    *(h4*)&xnxt[cl * 128 + ((nb8 ^ cl) & 15) * 8 + (gq & 1) * 4] = hv;
                }
            }
            if (FINAL || !last) __syncthreads();
            if constexpr (FINAL) {
                // cooperative dense copy-out: 4 KB contiguous per instruction
                const size_t t     = (size_t)c * LCH + g * 4 + s;
                const size_t xbase = (t * BS + b0) * 128;
#pragma unroll
                for (int p2 = 0; p2 < 2; ++p2) {
                    const int f   = p2 * 256 + tid;
                    const int row = f >> 5, j = f & 31;
                    f4 v = stage[(s & 1) * 512 + row * 32 + (j ^ (row & 7))];
                    __builtin_nontemporal_store(v, (f4*)&Xout[xbase + (size_t)f * 4]);
                    if (j == 31)
                        __builtin_nontemporal_store(v[3], &Yout[t * BS + b0 + row]);
                }
            }
            if (!last) {
                _Float16* tmp = xcur; xcur = xnxt; xnxt = tmp;
            }
        }
    }
}

// ---------------------------------------------------------------------------
// carry: Init[cc] = Init[cc-1] @ W^32 + F[cc-1], register style, 1 wave/block.
// ---------------------------------------------------------------------------
__global__ __launch_bounds__(64, 1)
void carry_kernel(const float* __restrict__ x0, char* __restrict__ ws, int n_steps)
{
    const int lane = threadIdx.x;
    const int cl = lane & 15, gq = lane >> 4;
    const int b0 = blockIdx.x * 16;

    const _Float16* W32 = (const _Float16*)(ws + WS_W32);
    const float* Fbuf   = (const float*)(ws + WS_F);
    float* Init         = (float*)(ws + WS_INIT);

    __shared__ __align__(16) _Float16 tbuf[16 * 128];

    h8 wf[8][4];
#pragma unroll
    for (int nt = 0; nt < 8; ++nt)
#pragma unroll
        for (int kt = 0; kt < 4; ++kt)
            wf[nt][kt] = *(const h8*)&W32[(nt * 16 + cl) * 128 + kt * 32 + gq * 8];

    h8 xf[4];
    {
        f4 iv[8];
#pragma unroll
        for (int nt = 0; nt < 8; ++nt)
            iv[nt] = *(const f4*)&x0[(size_t)(b0 + cl) * 128 + nt * 16 + gq * 4];
#pragma unroll
        for (int nt = 0; nt < 8; ++nt)
            *(f4*)&Init[(size_t)(b0 + cl) * 128 + nt * 16 + gq * 4] = iv[nt];
#pragma unroll
        for (int nt = 0; nt < 8; ++nt) {
            h4 hv;
#pragma unroll
            for (int r = 0; r < 4; ++r) hv[r] = (_Float16)iv[nt][r];
            *(h4*)&tbuf[cl * 128 + (((nt * 2 + (gq >> 1)) ^ cl) & 15) * 8 + (gq & 1) * 4] = hv;
        }
#pragma unroll
        for (int kt = 0; kt < 4; ++kt)
            xf[kt] = *(const h8*)&tbuf[cl * 128 + (((kt * 4 + gq) ^ cl) & 15) * 8];
    }

    for (int cc = 1; cc <= n_steps; ++cc) {
        f4 acc[8];
#pragma unroll
        for (int nt = 0; nt < 8; ++nt)
            acc[nt] = *(const f4*)&Fbuf[((size_t)(cc - 1) * BS + b0 + cl) * 128 + nt * 16 + gq * 4];
#pragma unroll
        for (int kt = 0; kt < 4; ++kt)
#pragma unroll
            for (int nt = 0; nt < 8; ++nt)
                acc[nt] = MFMA16(wf[nt][kt], xf[kt], acc[nt]);
#pragma unroll
        for (int nt = 0; nt < 8; ++nt)
            *(f4*)&Init[((size_t)cc * BS + b0 + cl) * 128 + nt * 16 + gq * 4] = acc[nt];
        if (cc < n_steps) {
#pragma unroll
            for (int nt = 0; nt < 8; ++nt) {
                h4 hv;
#pragma unroll
                for (int r = 0; r < 4; ++r) hv[r] = (_Float16)acc[nt][r];
                *(h4*)&tbuf[cl * 128 + (((nt * 2 + (gq >> 1)) ^ cl) & 15) * 8 + (gq & 1) * 4] = hv;
            }
#pragma unroll
            for (int kt = 0; kt < 4; ++kt)
                xf[kt] = *(const h8*)&tbuf[cl * 128 + (((kt * 4 + gq) ^ cl) & 15) * 8];
        }
    }
}

// ---------------------------------------------------------------------------
extern "C" void kernel_launch(void* const* d_in, const int* in_sizes, int n_in,
                              void* d_out, int out_size, void* d_ws, size_t ws_size,
                              hipStream_t stream)
{
    const float* x_in = (const float*)d_in[0];
    const float* Mfl  = (const float*)d_in[1];
    const float* DTi  = (const float*)d_in[2];
    const float* Din  = (const float*)d_in[3];
    const float* Aw   = (const float*)d_in[4];
    const float* As   = (const float*)d_in[5];
    const float* Bw   = (const float*)d_in[6];
    const float* Ew   = (const float*)d_in[7];
    const float* hf1  = (const float*)d_in[8];
    const float* hf2  = (const float*)d_in[9];
    char* ws    = (char*)d_ws;
    float* Xout = (float*)d_out;
    float* Yout = Xout + XTOT;

    prep_kernel<<<dim3(160), dim3(128), 0, stream>>>(Aw, As, hf1, hf2, Bw, Ew, ws);
    w32_kernel<<<dim3(1), dim3(256), 0, stream>>>(ws);

    // K1: fused MLP + local scan, chunks 0..30 -> F
    fused_scan<false><<<dim3(31 * 64), dim3(256), 0, stream>>>(Mfl, DTi, Din, ws,
                                                               nullptr, nullptr);
    // K2: carry propagation -> Init[0..31]
    carry_kernel<<<dim3(64), dim3(64), 0, stream>>>(x_in, ws, 31);
    // K3: fused MLP + true scan -> X, Y (dense staged stores)
    fused_scan<true><<<dim3(32 * 64), dim3(256), 0, stream>>>(Mfl, DTi, Din, ws,
                                                              Xout, Yout);
}